// Round 2
// baseline (497.584 us; speedup 1.0000x reference)
//
#include <hip/hip_runtime.h>

// Problem constants
#define DD    256        // descriptor dim
#define KK    64         // clusters
#define NPIX  262144     // H*W
#define NT    32         // tile columns
#define GRID  512        // blocks (2 per CU)
#define TPB   16         // tiles per block (GRID*TPB*NT == NPIX)
#define BLOCK 512        // 8 waves

// LDS strides (elements). All chosen so b64/b128 accesses stay aligned and
// read patterns are <=2-way bank conflicts (free per m136).
#define XDN_S 40         // Xdn: [256][40] bf16, 80B rows (16B-mult), reads 2-way
#define XND_S 264        // Xnd: [32][264] bf16, 528B rows (16B-mult)
#define W_S   264        // W:   [64][264] bf16
#define AB_S  40         // Abar:[64][40]  bf16, 80B rows
#define SV_S  129        // V stage: [64][129] f32 (half of d at a time)

typedef __attribute__((ext_vector_type(8))) short bf16x8;
typedef __attribute__((ext_vector_type(4))) float f32x4;

union Frag { bf16x8 v; int i[4]; };

__device__ __forceinline__ unsigned short f2bf(float f) {
    union { float f; unsigned u; } c; c.f = f;
    unsigned u = c.u;
    u += 0x7fffu + ((u >> 16) & 1u);       // round-to-nearest-even
    return (unsigned short)(u >> 16);
}
__device__ __forceinline__ int pack2(float a, float b) {
    return (int)((unsigned)f2bf(a) | ((unsigned)f2bf(b) << 16));
}

__global__ __launch_bounds__(BLOCK, 4)
void netvlad_fused(const float* __restrict__ x, const float* __restrict__ conv_w,
                   const float* __restrict__ conv_b, float* __restrict__ Vws,
                   float* __restrict__ asum_ws)
{
    __shared__ union {
        struct { short xdn[DD * XDN_S]; short xnd[NT * XND_S]; } a;  // 37376 B
        float sv[KK * SV_S];                                         // 33024 B
    } smA;
    __shared__ short Wl[KK * W_S];     // 33792 B
    __shared__ short Ab[KK * AB_S];    //  5120 B
    // total ~76.3 KB -> 2 blocks/CU

    const int t    = threadIdx.x;
    const int lane = t & 63;
    const int w    = t >> 6;        // wave 0..7
    const int l15  = lane & 15;
    const int q    = (lane >> 4) & 3;

    // ---- stage W (fp32 -> bf16) into LDS, once ----
    #pragma unroll
    for (int i = 0; i < 32; ++i) {
        int idx = t + BLOCK * i;                 // 0..16383
        int k = idx >> 8, d = idx & 255;
        Wl[k * W_S + d] = (short)f2bf(conv_w[idx]);
    }

    // bias registers for logits waves: k = 16*mt + 4*q + r
    float breg[4][4];
    if (w < 2) {
        #pragma unroll
        for (int mt = 0; mt < 4; ++mt)
            #pragma unroll
            for (int r = 0; r < 4; ++r)
                breg[mt][r] = conv_b[16 * mt + 4 * q + r];
    }

    // V accumulators: wave owns d rows [32w, 32w+32), all 64 k cols
    f32x4 acc[2][4];
    #pragma unroll
    for (int mi = 0; mi < 2; ++mi)
        #pragma unroll
        for (int ct = 0; ct < 4; ++ct)
            acc[mi][ct] = (f32x4){0.f, 0.f, 0.f, 0.f};

    float asum[4][4];
    #pragma unroll
    for (int mt = 0; mt < 4; ++mt)
        #pragma unroll
        for (int r = 0; r < 4; ++r) asum[mt][r] = 0.f;

    __syncthreads();

    // staging mapping: thread owns 4x4 patch: rows d=4g..4g+3, cols 4h..4h+3
    const int g = t >> 3;            // 0..63
    const int h = t & 7;             // 0..7

    // ---- prologue: prefetch tile 0 into registers ----
    float4 pre[4];
    {
        size_t n0 = (size_t)blockIdx.x * NT;
        #pragma unroll
        for (int jj = 0; jj < 4; ++jj)
            pre[jj] = *(const float4*)(x + (size_t)(4 * g + jj) * NPIX + n0 + 4 * h);
    }

    for (int it = 0; it < TPB; ++it) {
        __syncthreads();   // previous tile's LDS reads complete

        // ---- stage registers -> LDS (both layouts, bf16, all b64 writes) ----
        {
            const float* r0 = (const float*)&pre[0];
            const float* r1 = (const float*)&pre[1];
            const float* r2 = (const float*)&pre[2];
            const float* r3 = (const float*)&pre[3];
            #pragma unroll
            for (int jj = 0; jj < 4; ++jj) {
                const float* rr = (const float*)&pre[jj];
                int2 pk; pk.x = pack2(rr[0], rr[1]); pk.y = pack2(rr[2], rr[3]);
                *(int2*)&smA.a.xdn[(4 * g + jj) * XDN_S + 4 * h] = pk;
            }
            #pragma unroll
            for (int c = 0; c < 4; ++c) {
                int2 pk; pk.x = pack2(r0[c], r1[c]); pk.y = pack2(r2[c], r3[c]);
                *(int2*)&smA.a.xnd[(4 * h + c) * XND_S + 4 * g] = pk;
            }
        }

        // ---- prefetch next tile (stays in flight across barriers) ----
        if (it + 1 < TPB) {
            size_t n0 = ((size_t)blockIdx.x + (size_t)(it + 1) * GRID) * NT;
            #pragma unroll
            for (int jj = 0; jj < 4; ++jj)
                pre[jj] = *(const float4*)(x + (size_t)(4 * g + jj) * NPIX + n0 + 4 * h);
        }

        __syncthreads();   // staged tile visible

        // ---- logits + softmax (waves 0-1; wave owns n-tile w = 16 columns) ----
        if (w < 2) {
            f32x4 Lc[4];
            #pragma unroll
            for (int mt = 0; mt < 4; ++mt) Lc[mt] = (f32x4){0.f, 0.f, 0.f, 0.f};
            const int nloc = 16 * w + l15;
            #pragma unroll
            for (int ks = 0; ks < 8; ++ks) {
                Frag B = *(const Frag*)&smA.a.xnd[nloc * XND_S + 32 * ks + 8 * q];
                #pragma unroll
                for (int mt = 0; mt < 4; ++mt) {
                    Frag A = *(const Frag*)&Wl[(16 * mt + l15) * W_S + 32 * ks + 8 * q];
                    Lc[mt] = __builtin_amdgcn_mfma_f32_16x16x32_bf16(A.v, B.v, Lc[mt], 0, 0, 0);
                }
            }
            // bias + max
            float mx = -1e30f;
            #pragma unroll
            for (int mt = 0; mt < 4; ++mt)
                #pragma unroll
                for (int r = 0; r < 4; ++r) {
                    Lc[mt][r] += breg[mt][r];
                    mx = fmaxf(mx, Lc[mt][r]);
                }
            mx = fmaxf(mx, __shfl_xor(mx, 16));
            mx = fmaxf(mx, __shfl_xor(mx, 32));
            float s = 0.f;
            #pragma unroll
            for (int mt = 0; mt < 4; ++mt)
                #pragma unroll
                for (int r = 0; r < 4; ++r) {
                    float e = __expf(Lc[mt][r] - mx);
                    Lc[mt][r] = e;          // reuse regs
                    s += e;
                }
            s += __shfl_xor(s, 16);
            s += __shfl_xor(s, 32);
            float inv = 1.0f / s;
            #pragma unroll
            for (int mt = 0; mt < 4; ++mt)
                #pragma unroll
                for (int r = 0; r < 4; ++r) {
                    float a = Lc[mt][r] * inv;
                    asum[mt][r] += a;
                    Ab[(16 * mt + 4 * q + r) * AB_S + nloc] = (short)f2bf(a);
                }
        }

        __syncthreads();   // Abar visible

        // ---- VLAD GEMM: contraction = full 32-column tile, all 8 waves ----
        {
            Frag Bf[4];
            #pragma unroll
            for (int ct = 0; ct < 4; ++ct)
                Bf[ct] = *(const Frag*)&Ab[(16 * ct + l15) * AB_S + 8 * q];
            #pragma unroll
            for (int mi = 0; mi < 2; ++mi) {
                Frag Af = *(const Frag*)&smA.a.xdn[(32 * w + 16 * mi + l15) * XDN_S + 8 * q];
                #pragma unroll
                for (int ct = 0; ct < 4; ++ct)
                    acc[mi][ct] = __builtin_amdgcn_mfma_f32_16x16x32_bf16(Af.v, Bf[ct].v, acc[mi][ct], 0, 0, 0);
            }
        }
    }

    // ---- epilogue: V partial -> LDS (two d-halves) -> coalesced atomics ----
    #pragma unroll
    for (int H = 0; H < 2; ++H) {
        __syncthreads();   // previous reads of smA done
        if ((w >> 2) == H) {
            #pragma unroll
            for (int mi = 0; mi < 2; ++mi)
                #pragma unroll
                for (int ct = 0; ct < 4; ++ct)
                    #pragma unroll
                    for (int r = 0; r < 4; ++r) {
                        int k = 16 * ct + l15;
                        int dl = 32 * w + 16 * mi + 4 * q + r - 128 * H;
                        smA.sv[k * SV_S + dl] = acc[mi][ct][r];
                    }
        }
        __syncthreads();
        #pragma unroll
        for (int i = 0; i < 16; ++i) {
            int idx = t + BLOCK * i;       // 0..8191
            int k = idx >> 7, dl = idx & 127;
            atomicAdd(&Vws[k * DD + 128 * H + dl], smA.sv[k * SV_S + dl]);
        }
    }
    if (w < 2) {
        #pragma unroll
        for (int mt = 0; mt < 4; ++mt)
            #pragma unroll
            for (int r = 0; r < 4; ++r) {
                float v = asum[mt][r];
                v += __shfl_xor(v, 1);
                v += __shfl_xor(v, 2);
                v += __shfl_xor(v, 4);
                v += __shfl_xor(v, 8);
                if (l15 == 0) atomicAdd(&asum_ws[16 * mt + 4 * q + r], v);
            }
    }
}

__global__ __launch_bounds__(1024)
void netvlad_finalize(const float* __restrict__ Vws, const float* __restrict__ asum_ws,
                      const float* __restrict__ c, float* __restrict__ y)
{
    __shared__ float sV[KK * DD];
    __shared__ float sa[KK];
    __shared__ float colf[DD];
    __shared__ float rowf[KK];
    const int t = threadIdx.x;

    if (t < KK) sa[t] = asum_ws[t];
    __syncthreads();

    #pragma unroll
    for (int i = 0; i < 16; ++i) {
        int idx = t + 1024 * i;
        sV[idx] = Vws[idx] - c[idx] * sa[idx >> 8];
    }
    __syncthreads();

    if (t < DD) {   // column (d) norms over k
        float s = 0.f;
        for (int k = 0; k < KK; ++k) { float v = sV[k * DD + t]; s += v * v; }
        colf[t] = 1.0f / fmaxf(sqrtf(s), 1e-12f);
    }
    __syncthreads();

    #pragma unroll
    for (int i = 0; i < 16; ++i) {
        int idx = t + 1024 * i;
        sV[idx] *= colf[idx & 255];
    }
    __syncthreads();

    {   // row (k) norms over d: 16 threads per row
        int k = t >> 4, p = t & 15;
        float s = 0.f;
        #pragma unroll
        for (int j = 0; j < 16; ++j) { float v = sV[k * DD + p + 16 * j]; s += v * v; }
        s += __shfl_xor(s, 1);
        s += __shfl_xor(s, 2);
        s += __shfl_xor(s, 4);
        s += __shfl_xor(s, 8);
        if (p == 0) rowf[k] = 1.0f / fmaxf(sqrtf(s), 1e-12f);
    }
    __syncthreads();

    #pragma unroll
    for (int i = 0; i < 16; ++i) {
        int idx = t + 1024 * i;
        y[idx] = sV[idx] * rowf[idx >> 8];
    }
}

extern "C" void kernel_launch(void* const* d_in, const int* in_sizes, int n_in,
                              void* d_out, int out_size, void* d_ws, size_t ws_size,
                              hipStream_t stream) {
    const float* x      = (const float*)d_in[0];
    const float* c      = (const float*)d_in[1];
    const float* conv_w = (const float*)d_in[2];
    const float* conv_b = (const float*)d_in[3];
    float* y   = (float*)d_out;
    float* Vws = (float*)d_ws;
    float* asum_ws = Vws + KK * DD;

    hipMemsetAsync(d_ws, 0, (KK * DD + KK) * sizeof(float), stream);
    netvlad_fused<<<GRID, BLOCK, 0, stream>>>(x, conv_w, conv_b, Vws, asum_ws);
    netvlad_finalize<<<1, 1024, 0, stream>>>(Vws, asum_ws, c, y);
}

// Round 3
// 460.214 us; speedup vs baseline: 1.0812x; 1.0812x over previous
//
#include <hip/hip_runtime.h>

// Problem constants
#define DD    256        // descriptor dim
#define KK    64         // clusters
#define NPIX  262144     // H*W
#define NW    256        // n-window per block (1 KB/row contiguous reads)
#define GRID  1024       // NW * GRID == NPIX
#define BLOCK 512        // 8 waves
#define NREP  16         // V-partial replicas (kills atomic contention)

// LDS strides (elements)
#define W_S   264        // W:    [64][264] bf16 (row 528 B, 16B-mult)
#define AB_S  264        // abar: [64][264] bf16 (same bytes as W -> union)
#define XC_S  40         // chunk rows: 40 shorts = 80 B (16B-mult, good banks)
#define SV_S  129        // V stage: [64][129] f32 (half of d at a time)

typedef __attribute__((ext_vector_type(8))) short bf16x8;
typedef __attribute__((ext_vector_type(4))) float f32x4;

union Frag { bf16x8 v; int i[4]; };

__device__ __forceinline__ unsigned short f2bf(float f) {
    union { float f; unsigned u; } c; c.f = f;
    unsigned u = c.u;
    u += 0x7fffu + ((u >> 16) & 1u);       // round-to-nearest-even
    return (unsigned short)(u >> 16);
}
__device__ __forceinline__ int pack2(float a, float b) {
    return (int)((unsigned)f2bf(a) | ((unsigned)f2bf(b) << 16));
}

__global__ __launch_bounds__(BLOCK, 4)
void netvlad_fused(const float* __restrict__ x, const float* __restrict__ conv_w,
                   const float* __restrict__ conv_b, float* __restrict__ Vrep,
                   float* __restrict__ asum_rep)
{
    __shared__ union {
        short W[KK * W_S];     // logits phase (33792 B)
        short Ab[KK * AB_S];   // after softmax (same 33792 B -- W is dead)
        float sv[KK * SV_S];   // epilogue (33024 B)
    } U1;
    __shared__ short U2[2][10240];  // 40960 B: logits = 8 wave-private 32x40 slices
                                    //          VLAD  = block-shared xdn 256x40
    // total 74752 B -> 2 blocks/CU

    const int t    = threadIdx.x;
    const int lane = t & 63;
    const int w    = t >> 6;        // wave 0..7
    const int l15  = lane & 15;
    const int q    = (lane >> 4) & 3;
    const int rep  = blockIdx.x & (NREP - 1);
    const size_t n0 = (size_t)blockIdx.x * NW;

    // ---- logits-phase load mapping: wave-private 32-col slice ----
    const int dg = lane >> 3;            // 0..7  (4 d-rows each)
    const int ng = lane & 7;             // 0..7  (4 n-cols each)
    const size_t nself = n0 + 32 * w + 4 * ng;

    // prefetch d-chunk 0 (issued before W staging so it overlaps)
    float4 pr[2][4];
    #pragma unroll
    for (int j = 0; j < 4; ++j)
        pr[0][j] = *(const float4*)(x + (size_t)(4 * dg + j) * NPIX + nself);

    // ---- stage W (fp32 -> bf16) into LDS, once ----
    #pragma unroll
    for (int i = 0; i < 32; ++i) {
        int idx = t + BLOCK * i;                 // 0..16383
        U1.W[(idx >> 8) * W_S + (idx & 255)] = (short)f2bf(conv_w[idx]);
    }

    float breg[4][4];
    #pragma unroll
    for (int mt = 0; mt < 4; ++mt)
        #pragma unroll
        for (int r = 0; r < 4; ++r)
            breg[mt][r] = conv_b[16 * mt + 4 * q + r];

    __syncthreads();   // W visible (also drains chunk-0 loads; once, harmless)

    // ================= PHASE 1: logits, wave-private, NO barriers =========
    f32x4 Lc[2][4];
    #pragma unroll
    for (int nt = 0; nt < 2; ++nt)
        #pragma unroll
        for (int mt = 0; mt < 4; ++mt)
            Lc[nt][mt] = (f32x4){0.f, 0.f, 0.f, 0.f};

    #pragma unroll
    for (int ch = 0; ch < 8; ++ch) {
        const int cur = ch & 1;
        short* slice = &U2[cur][w * 1280];

        // stage pr[cur] -> private LDS slice (n-major, micro-transposed)
        #pragma unroll
        for (int c = 0; c < 4; ++c) {
            int2 pk;
            pk.x = pack2(((const float*)&pr[cur][0])[c], ((const float*)&pr[cur][1])[c]);
            pk.y = pack2(((const float*)&pr[cur][2])[c], ((const float*)&pr[cur][3])[c]);
            *(int2*)&slice[(4 * ng + c) * XC_S + 4 * dg] = pk;
        }

        // issue next chunk's loads -- free-running, no barrier will drain them
        if (ch < 7) {
            #pragma unroll
            for (int j = 0; j < 4; ++j)
                pr[cur ^ 1][j] = *(const float4*)(x + (size_t)(32 * (ch + 1) + 4 * dg + j) * NPIX + nself);
        }

        // frags + MFMA (contraction over this d-chunk, K=32)
        Frag Bv[2];
        #pragma unroll
        for (int nt = 0; nt < 2; ++nt)
            Bv[nt] = *(const Frag*)&slice[(16 * nt + l15) * XC_S + 8 * q];
        #pragma unroll
        for (int mt = 0; mt < 4; ++mt) {
            Frag A = *(const Frag*)&U1.W[(16 * mt + l15) * W_S + 32 * ch + 8 * q];
            #pragma unroll
            for (int nt = 0; nt < 2; ++nt)
                Lc[nt][mt] = __builtin_amdgcn_mfma_f32_16x16x32_bf16(A.v, Bv[nt].v, Lc[nt][mt], 0, 0, 0);
        }
    }

    // ---- softmax over k (in-register, wave-local) ----
    #pragma unroll
    for (int nt = 0; nt < 2; ++nt) {
        float mx = -1e30f;
        #pragma unroll
        for (int mt = 0; mt < 4; ++mt)
            #pragma unroll
            for (int r = 0; r < 4; ++r) {
                Lc[nt][mt][r] += breg[mt][r];
                mx = fmaxf(mx, Lc[nt][mt][r]);
            }
        mx = fmaxf(mx, __shfl_xor(mx, 16));
        mx = fmaxf(mx, __shfl_xor(mx, 32));
        float s = 0.f;
        #pragma unroll
        for (int mt = 0; mt < 4; ++mt)
            #pragma unroll
            for (int r = 0; r < 4; ++r) {
                float e = __expf(Lc[nt][mt][r] - mx);
                Lc[nt][mt][r] = e;
                s += e;
            }
        s += __shfl_xor(s, 16);
        s += __shfl_xor(s, 32);
        float inv = 1.0f / s;
        #pragma unroll
        for (int mt = 0; mt < 4; ++mt)
            #pragma unroll
            for (int r = 0; r < 4; ++r)
                Lc[nt][mt][r] *= inv;
    }

    // asum partials -> replica (tiny, spread over 16 replicas)
    #pragma unroll
    for (int mt = 0; mt < 4; ++mt)
        #pragma unroll
        for (int r = 0; r < 4; ++r) {
            float v = Lc[0][mt][r] + Lc[1][mt][r];
            v += __shfl_xor(v, 1);
            v += __shfl_xor(v, 2);
            v += __shfl_xor(v, 4);
            v += __shfl_xor(v, 8);
            if (l15 == 0) atomicAdd(&asum_rep[rep * KK + 16 * mt + 4 * q + r], v);
        }

    __syncthreads();   // everyone done reading W -> abar may overwrite it

    // abar -> LDS (bf16)
    #pragma unroll
    for (int nt = 0; nt < 2; ++nt)
        #pragma unroll
        for (int mt = 0; mt < 4; ++mt)
            #pragma unroll
            for (int r = 0; r < 4; ++r)
                U1.Ab[(16 * mt + 4 * q + r) * AB_S + 32 * w + 16 * nt + l15] =
                    (short)f2bf(Lc[nt][mt][r]);

    // V accumulators: wave owns d rows [32w, 32w+32), all 64 k cols
    f32x4 acc[2][4];
    #pragma unroll
    for (int mi = 0; mi < 2; ++mi)
        #pragma unroll
        for (int ct = 0; ct < 4; ++ct)
            acc[mi][ct] = (f32x4){0.f, 0.f, 0.f, 0.f};

    __syncthreads();   // abar visible

    // ================= PHASE 2: VLAD GEMM (x re-read is L2/L3-warm) =======
    const int g = t >> 3;            // 0..63 (4 d-rows each -> all 256 d)
    const int h = t & 7;             // 0..7  (4 n-cols each -> 32-col sub)
    float4 pv[2][4];
    #pragma unroll
    for (int jj = 0; jj < 4; ++jj)
        pv[0][jj] = *(const float4*)(x + (size_t)(4 * g + jj) * NPIX + n0 + 4 * h);

    #pragma unroll
    for (int sub = 0; sub < 8; ++sub) {
        const int cur = sub & 1;
        // stage pv[cur] -> block-shared xdn [256][40]
        #pragma unroll
        for (int jj = 0; jj < 4; ++jj) {
            const float* rr = (const float*)&pv[cur][jj];
            int2 pk; pk.x = pack2(rr[0], rr[1]); pk.y = pack2(rr[2], rr[3]);
            *(int2*)&U2[cur][(4 * g + jj) * XC_S + 4 * h] = pk;
        }
        __syncthreads();   // staged sub visible (drains nothing in flight)
        // issue next sub's loads AFTER the barrier -> in flight during MFMA
        if (sub < 7) {
            #pragma unroll
            for (int jj = 0; jj < 4; ++jj)
                pv[cur ^ 1][jj] = *(const float4*)(x + (size_t)(4 * g + jj) * NPIX
                                                   + n0 + 32 * (sub + 1) + 4 * h);
        }
        Frag Bf[4];
        #pragma unroll
        for (int ct = 0; ct < 4; ++ct)
            Bf[ct] = *(const Frag*)&U1.Ab[(16 * ct + l15) * AB_S + 32 * sub + 8 * q];
        #pragma unroll
        for (int mi = 0; mi < 2; ++mi) {
            Frag Af = *(const Frag*)&U2[cur][(32 * w + 16 * mi + l15) * XC_S + 8 * q];
            #pragma unroll
            for (int ct = 0; ct < 4; ++ct)
                acc[mi][ct] = __builtin_amdgcn_mfma_f32_16x16x32_bf16(Af.v, Bf[ct].v, acc[mi][ct], 0, 0, 0);
        }
    }

    // ---- epilogue: V partial -> LDS (two d-halves) -> replica atomics ----
    #pragma unroll
    for (int H = 0; H < 2; ++H) {
        __syncthreads();   // previous users of U1/U2 done
        if ((w >> 2) == H) {
            #pragma unroll
            for (int mi = 0; mi < 2; ++mi)
                #pragma unroll
                for (int ct = 0; ct < 4; ++ct)
                    #pragma unroll
                    for (int r = 0; r < 4; ++r) {
                        int k  = 16 * ct + l15;
                        int dl = 32 * w + 16 * mi + 4 * q + r - 128 * H;
                        U1.sv[k * SV_S + dl] = acc[mi][ct][r];
                    }
        }
        __syncthreads();
        #pragma unroll
        for (int i = 0; i < 16; ++i) {
            int idx = t + BLOCK * i;       // 0..8191
            int k = idx >> 7, dl = idx & 127;
            atomicAdd(&Vrep[rep * (KK * DD) + k * DD + 128 * H + dl], U1.sv[k * SV_S + dl]);
        }
    }
}

__global__ __launch_bounds__(256)
void netvlad_reduce(const float* __restrict__ Vrep, const float* __restrict__ asum_rep,
                    float* __restrict__ Vred, float* __restrict__ asum_red)
{
    int o = blockIdx.x * 256 + threadIdx.x;
    float s = 0.f;
    #pragma unroll
    for (int r = 0; r < NREP; ++r) s += Vrep[r * (KK * DD) + o];
    Vred[o] = s;
    if (blockIdx.x == 0 && threadIdx.x < KK) {
        float a = 0.f;
        #pragma unroll
        for (int r = 0; r < NREP; ++r) a += asum_rep[r * KK + threadIdx.x];
        asum_red[threadIdx.x] = a;
    }
}

__global__ __launch_bounds__(1024)
void netvlad_finalize(const float* __restrict__ Vws, const float* __restrict__ asum_ws,
                      const float* __restrict__ c, float* __restrict__ y)
{
    __shared__ float sV[KK * DD];
    __shared__ float sa[KK];
    __shared__ float colf[DD];
    __shared__ float rowf[KK];
    const int t = threadIdx.x;

    if (t < KK) sa[t] = asum_ws[t];
    __syncthreads();

    #pragma unroll
    for (int i = 0; i < 16; ++i) {
        int idx = t + 1024 * i;
        sV[idx] = Vws[idx] - c[idx] * sa[idx >> 8];
    }
    __syncthreads();

    if (t < DD) {   // column (d) norms over k
        float s = 0.f;
        for (int k = 0; k < KK; ++k) { float v = sV[k * DD + t]; s += v * v; }
        colf[t] = 1.0f / fmaxf(sqrtf(s), 1e-12f);
    }
    __syncthreads();

    #pragma unroll
    for (int i = 0; i < 16; ++i) {
        int idx = t + 1024 * i;
        sV[idx] *= colf[idx & 255];
    }
    __syncthreads();

    {   // row (k) norms over d: 16 threads per row
        int k = t >> 4, p = t & 15;
        float s = 0.f;
        #pragma unroll
        for (int j = 0; j < 16; ++j) { float v = sV[k * DD + p + 16 * j]; s += v * v; }
        s += __shfl_xor(s, 1);
        s += __shfl_xor(s, 2);
        s += __shfl_xor(s, 4);
        s += __shfl_xor(s, 8);
        if (p == 0) rowf[k] = 1.0f / fmaxf(sqrtf(s), 1e-12f);
    }
    __syncthreads();

    #pragma unroll
    for (int i = 0; i < 16; ++i) {
        int idx = t + 1024 * i;
        y[idx] = sV[idx] * rowf[idx >> 8];
    }
}

extern "C" void kernel_launch(void* const* d_in, const int* in_sizes, int n_in,
                              void* d_out, int out_size, void* d_ws, size_t ws_size,
                              hipStream_t stream) {
    const float* x      = (const float*)d_in[0];
    const float* c      = (const float*)d_in[1];
    const float* conv_w = (const float*)d_in[2];
    const float* conv_b = (const float*)d_in[3];
    float* y = (float*)d_out;

    float* Vrep     = (float*)d_ws;
    float* asum_rep = Vrep + NREP * KK * DD;
    float* Vred     = asum_rep + NREP * KK;
    float* asum_red = Vred + KK * DD;

    hipMemsetAsync(d_ws, 0, (size_t)NREP * (KK * DD + KK) * sizeof(float), stream);
    netvlad_fused<<<GRID, BLOCK, 0, stream>>>(x, conv_w, conv_b, Vrep, asum_rep);
    netvlad_reduce<<<(KK * DD) / 256, 256, 0, stream>>>(Vrep, asum_rep, Vred, asum_red);
    netvlad_finalize<<<1, 1024, 0, stream>>>(Vred, asum_red, c, y);
}

// Round 4
// 460.187 us; speedup vs baseline: 1.0813x; 1.0001x over previous
//
#include <hip/hip_runtime.h>
#include <hip/hip_bf16.h>

// Problem constants
#define DD    256        // descriptor dim
#define KK    64         // clusters
#define NPIX  262144     // H*W
#define NW    512        // n-window per block (2 KB/row contiguous)
#define GRID  512        // NW * GRID == NPIX
#define BLOCK 1024       // 16 waves, 1 block/CU (LDS-bound)
#define NREP  16         // V-partial replicas

// LDS strides (elements)
#define W_S   264        // W:    [64][264] bf16 (row 528 B, 16B-mult)
#define AB_S  520        // abar: [64][520] bf16 (row 1040 B, 16B-mult)
#define XC_S  40         // phase-1 slice rows: 40 shorts = 80 B (16B-mult)
#define SV_S  129        // V stage: [64][129] f32 (half of d at a time)

typedef __attribute__((ext_vector_type(8))) short bf16x8;
typedef __attribute__((ext_vector_type(4))) float f32x4;

union Frag { bf16x8 v; int i[4]; };

__device__ __forceinline__ int cvtpk(float a, float b) {
    // packed f32->bf16 RNE; lowers to v_cvt_pk_bf16_f32 on gfx950
    __hip_bfloat162 h = __float22bfloat162_rn(float2{a, b});
    int r; __builtin_memcpy(&r, &h, 4); return r;  // low short = a
}

__global__ __launch_bounds__(BLOCK, 4)
void netvlad_fused(const float* __restrict__ x, const float* __restrict__ conv_w,
                   const float* __restrict__ conv_b, float* __restrict__ Vrep,
                   float* __restrict__ asum_rep)
{
    __shared__ short Wl[KK * W_S];    // 33792 B
    __shared__ short Ab[KK * AB_S];   // 66560 B
    __shared__ union {
        short slice[16 * 32 * XC_S];  // 40960 B: 16 wave-private 32x40 xnd slices
        float sv[KK * SV_S];          // 33024 B: epilogue staging
    } U2;
    // total 141312 B -> 1 block/CU

    const int t    = threadIdx.x;
    const int lane = t & 63;
    const int w    = t >> 6;        // wave 0..15
    const int l15  = lane & 15;
    const int q    = (lane >> 4) & 3;
    const int rep  = blockIdx.x & (NREP - 1);
    const size_t n0 = (size_t)blockIdx.x * NW;

    // ---- phase-1 load mapping: wave-private 32-col slice, chunks of 32 d ----
    const int dg = lane >> 3;            // 0..7  (4 d-rows each)
    const int ng = lane & 7;             // 0..7  (4 n-cols each)
    const size_t nself = n0 + 32 * w + 4 * ng;

    // prologue: chunk 0 loads (overlap W staging)
    float4 pr[2][4];
    #pragma unroll
    for (int j = 0; j < 4; ++j)
        pr[0][j] = *(const float4*)(x + (size_t)(4 * dg + j) * NPIX + nself);

    // ---- stage W (fp32 -> bf16) into LDS, once ----
    #pragma unroll
    for (int i = 0; i < 16; ++i) {
        int idx = t + BLOCK * i;                 // 0..16383
        float wv = conv_w[idx];
        __hip_bfloat16 hb = __float2bfloat16(wv);
        short s; __builtin_memcpy(&s, &hb, 2);
        Wl[(idx >> 8) * W_S + (idx & 255)] = s;
    }

    // prologue: chunk 1 loads
    #pragma unroll
    for (int j = 0; j < 4; ++j)
        pr[1][j] = *(const float4*)(x + (size_t)(32 + 4 * dg + j) * NPIX + nself);

    float breg[4][4];
    #pragma unroll
    for (int mt = 0; mt < 4; ++mt)
        #pragma unroll
        for (int r = 0; r < 4; ++r)
            breg[mt][r] = conv_b[16 * mt + 4 * q + r];

    __syncthreads();   // W visible

    // ================= PHASE 1: logits, wave-private, NO barriers =========
    f32x4 Lc[2][4];
    #pragma unroll
    for (int nt = 0; nt < 2; ++nt)
        #pragma unroll
        for (int mt = 0; mt < 4; ++mt)
            Lc[nt][mt] = (f32x4){0.f, 0.f, 0.f, 0.f};

    short* slice = &U2.slice[w * (32 * XC_S)];

    #pragma unroll
    for (int ch = 0; ch < 8; ++ch) {
        const int cur = ch & 1;

        // stage pr[cur] -> private slice (n-major micro-transpose), b64 writes
        {
            const float* r0 = (const float*)&pr[cur][0];
            const float* r1 = (const float*)&pr[cur][1];
            const float* r2 = (const float*)&pr[cur][2];
            const float* r3 = (const float*)&pr[cur][3];
            #pragma unroll
            for (int c = 0; c < 4; ++c) {
                int2 pk; pk.x = cvtpk(r0[c], r1[c]); pk.y = cvtpk(r2[c], r3[c]);
                *(int2*)&slice[(4 * ng + c) * XC_S + 4 * dg] = pk;
            }
        }

        // depth-2 prefetch: issue chunk ch+2 (regs just freed by staging)
        if (ch < 6) {
            #pragma unroll
            for (int j = 0; j < 4; ++j)
                pr[cur][j] = *(const float4*)(x + (size_t)(32 * (ch + 2) + 4 * dg + j) * NPIX + nself);
        }

        // frags + MFMA (contraction over this 32-d chunk)
        Frag Bv[2];
        #pragma unroll
        for (int nt = 0; nt < 2; ++nt)
            Bv[nt] = *(const Frag*)&slice[(16 * nt + l15) * XC_S + 8 * q];
        #pragma unroll
        for (int mt = 0; mt < 4; ++mt) {
            Frag A = *(const Frag*)&Wl[(16 * mt + l15) * W_S + 32 * ch + 8 * q];
            #pragma unroll
            for (int nt = 0; nt < 2; ++nt)
                Lc[nt][mt] = __builtin_amdgcn_mfma_f32_16x16x32_bf16(A.v, Bv[nt].v, Lc[nt][mt], 0, 0, 0);
        }
    }

    // ---- softmax over k (in-register, wave-local) ----
    #pragma unroll
    for (int nt = 0; nt < 2; ++nt) {
        float mx = -1e30f;
        #pragma unroll
        for (int mt = 0; mt < 4; ++mt)
            #pragma unroll
            for (int r = 0; r < 4; ++r) {
                Lc[nt][mt][r] += breg[mt][r];
                mx = fmaxf(mx, Lc[nt][mt][r]);
            }
        mx = fmaxf(mx, __shfl_xor(mx, 16));
        mx = fmaxf(mx, __shfl_xor(mx, 32));
        float s = 0.f;
        #pragma unroll
        for (int mt = 0; mt < 4; ++mt)
            #pragma unroll
            for (int r = 0; r < 4; ++r) {
                float e = __expf(Lc[nt][mt][r] - mx);
                Lc[nt][mt][r] = e;
                s += e;
            }
        s += __shfl_xor(s, 16);
        s += __shfl_xor(s, 32);
        float inv = 1.0f / s;
        #pragma unroll
        for (int mt = 0; mt < 4; ++mt)
            #pragma unroll
            for (int r = 0; r < 4; ++r)
                Lc[nt][mt][r] *= inv;
    }

    // asum partials (sum over this wave's 32 cols)
    #pragma unroll
    for (int mt = 0; mt < 4; ++mt)
        #pragma unroll
        for (int r = 0; r < 4; ++r) {
            float v = Lc[0][mt][r] + Lc[1][mt][r];
            v += __shfl_xor(v, 1);
            v += __shfl_xor(v, 2);
            v += __shfl_xor(v, 4);
            v += __shfl_xor(v, 8);
            if (l15 == 0) atomicAdd(&asum_rep[rep * KK + 16 * mt + 4 * q + r], v);
        }

    // abar -> LDS (bf16), wave-private columns
    #pragma unroll
    for (int nt = 0; nt < 2; ++nt)
        #pragma unroll
        for (int mt = 0; mt < 4; ++mt)
            #pragma unroll
            for (int r = 0; r < 4; ++r) {
                __hip_bfloat16 hb = __float2bfloat16(Lc[nt][mt][r]);
                short s; __builtin_memcpy(&s, &hb, 2);
                Ab[(16 * mt + 4 * q + r) * AB_S + 32 * w + 16 * nt + l15] = s;
            }

    __syncthreads();   // ALL abar visible -- the only mid-kernel barrier

    // ========= PHASE 2: VLAD GEMM, direct-load A frags, NO LDS, NO barriers =
    // lane l15 owns d-row 16w+l15; its float4 loads ARE the A-fragment.
    f32x4 acc[4];
    #pragma unroll
    for (int ct = 0; ct < 4; ++ct) acc[ct] = (f32x4){0.f, 0.f, 0.f, 0.f};

    const float* xrow = x + (size_t)(16 * w + l15) * NPIX + n0 + 8 * q;
    float4 pv[2][2];
    pv[0][0] = *(const float4*)(xrow + 0);
    pv[0][1] = *(const float4*)(xrow + 4);
    pv[1][0] = *(const float4*)(xrow + 32);
    pv[1][1] = *(const float4*)(xrow + 36);

    #pragma unroll
    for (int s = 0; s < 16; ++s) {
        const int cur = s & 1;
        Frag Af;
        Af.i[0] = cvtpk(pv[cur][0].x, pv[cur][0].y);
        Af.i[1] = cvtpk(pv[cur][0].z, pv[cur][0].w);
        Af.i[2] = cvtpk(pv[cur][1].x, pv[cur][1].y);
        Af.i[3] = cvtpk(pv[cur][1].z, pv[cur][1].w);
        if (s < 14) {   // depth-2 prefetch
            pv[cur][0] = *(const float4*)(xrow + 32 * (s + 2));
            pv[cur][1] = *(const float4*)(xrow + 32 * (s + 2) + 4);
        }
        Frag Bf[4];
        #pragma unroll
        for (int ct = 0; ct < 4; ++ct)
            Bf[ct] = *(const Frag*)&Ab[(16 * ct + l15) * AB_S + 32 * s + 8 * q];
        #pragma unroll
        for (int ct = 0; ct < 4; ++ct)
            acc[ct] = __builtin_amdgcn_mfma_f32_16x16x32_bf16(Af.v, Bf[ct].v, acc[ct], 0, 0, 0);
    }

    // ---- epilogue: V partial -> LDS (two d-halves) -> replica atomics ----
    // acc element (ct, r): k = 16ct + l15, d = 16w + 4q + r
    #pragma unroll
    for (int H = 0; H < 2; ++H) {
        __syncthreads();
        if ((w >> 3) == H) {
            #pragma unroll
            for (int ct = 0; ct < 4; ++ct)
                #pragma unroll
                for (int r = 0; r < 4; ++r) {
                    int k  = 16 * ct + l15;
                    int dl = 16 * w + 4 * q + r - 128 * H;
                    U2.sv[k * SV_S + dl] = acc[ct][r];
                }
        }
        __syncthreads();
        #pragma unroll
        for (int i = 0; i < 8; ++i) {
            int idx = t + BLOCK * i;       // 0..8191
            int k = idx >> 7, dl = idx & 127;
            atomicAdd(&Vrep[rep * (KK * DD) + k * DD + 128 * H + dl], U2.sv[k * SV_S + dl]);
        }
    }
}

__global__ __launch_bounds__(256)
void netvlad_reduce(const float* __restrict__ Vrep, const float* __restrict__ asum_rep,
                    float* __restrict__ Vred, float* __restrict__ asum_red)
{
    int o = blockIdx.x * 256 + threadIdx.x;
    float s = 0.f;
    #pragma unroll
    for (int r = 0; r < NREP; ++r) s += Vrep[r * (KK * DD) + o];
    Vred[o] = s;
    if (blockIdx.x == 0 && threadIdx.x < KK) {
        float a = 0.f;
        #pragma unroll
        for (int r = 0; r < NREP; ++r) a += asum_rep[r * KK + threadIdx.x];
        asum_red[threadIdx.x] = a;
    }
}

__global__ __launch_bounds__(1024)
void netvlad_finalize(const float* __restrict__ Vws, const float* __restrict__ asum_ws,
                      const float* __restrict__ c, float* __restrict__ y)
{
    __shared__ float sV[KK * DD];
    __shared__ float sa[KK];
    __shared__ float colf[DD];
    __shared__ float rowf[KK];
    const int t = threadIdx.x;

    if (t < KK) sa[t] = asum_ws[t];
    __syncthreads();

    #pragma unroll
    for (int i = 0; i < 16; ++i) {
        int idx = t + 1024 * i;
        sV[idx] = Vws[idx] - c[idx] * sa[idx >> 8];
    }
    __syncthreads();

    if (t < DD) {   // column (d) norms over k
        float s = 0.f;
        for (int k = 0; k < KK; ++k) { float v = sV[k * DD + t]; s += v * v; }
        colf[t] = 1.0f / fmaxf(sqrtf(s), 1e-12f);
    }
    __syncthreads();

    #pragma unroll
    for (int i = 0; i < 16; ++i) {
        int idx = t + 1024 * i;
        sV[idx] *= colf[idx & 255];
    }
    __syncthreads();

    {   // row (k) norms over d: 16 threads per row
        int k = t >> 4, p = t & 15;
        float s = 0.f;
        #pragma unroll
        for (int j = 0; j < 16; ++j) { float v = sV[k * DD + p + 16 * j]; s += v * v; }
        s += __shfl_xor(s, 1);
        s += __shfl_xor(s, 2);
        s += __shfl_xor(s, 4);
        s += __shfl_xor(s, 8);
        if (p == 0) rowf[k] = 1.0f / fmaxf(sqrtf(s), 1e-12f);
    }
    __syncthreads();

    #pragma unroll
    for (int i = 0; i < 16; ++i) {
        int idx = t + 1024 * i;
        y[idx] = sV[idx] * rowf[idx >> 8];
    }
}

extern "C" void kernel_launch(void* const* d_in, const int* in_sizes, int n_in,
                              void* d_out, int out_size, void* d_ws, size_t ws_size,
                              hipStream_t stream) {
    const float* x      = (const float*)d_in[0];
    const float* c      = (const float*)d_in[1];
    const float* conv_w = (const float*)d_in[2];
    const float* conv_b = (const float*)d_in[3];
    float* y = (float*)d_out;

    float* Vrep     = (float*)d_ws;
    float* asum_rep = Vrep + NREP * KK * DD;
    float* Vred     = asum_rep + NREP * KK;
    float* asum_red = Vred + KK * DD;

    hipMemsetAsync(d_ws, 0, (size_t)NREP * (KK * DD + KK) * sizeof(float), stream);
    netvlad_fused<<<GRID, BLOCK, 0, stream>>>(x, conv_w, conv_b, Vrep, asum_rep);
    netvlad_reduce<<<(KK * DD) / 256, 256, 0, stream>>>(Vrep, asum_rep, Vred, asum_red);
    netvlad_finalize<<<1, 1024, 0, stream>>>(Vred, asum_red, c, y);
}